// Round 7
// baseline (549.678 us; speedup 1.0000x reference)
//
#include <hip/hip_runtime.h>
#include <hip/hip_bf16.h>
#include <stdint.h>

#define M_MOL 128
#define L_SEQ 256
#define H_DIM 768
#define NH_   12
#define HD_   64
#define N_TOT (M_MOL * L_SEQ)

typedef __attribute__((ext_vector_type(8))) short bf16x8;
typedef __attribute__((ext_vector_type(4))) float f32x4;
typedef __attribute__((ext_vector_type(8))) unsigned short u16x8;
typedef __hip_bfloat16 bf16;

__device__ __forceinline__ float bf2f(bf16 x){ return __bfloat162float(x); }
__device__ __forceinline__ bf16 f2bf(float x){ return __float2bfloat16(x); }
__device__ __forceinline__ float bfbits2f(unsigned short u){
    return __uint_as_float(((unsigned)u) << 16);
}
__device__ __forceinline__ unsigned pk2(float lo, float hi){
    bf16 a = f2bf(lo), b = f2bf(hi);
    unsigned short ua, ub;
    __builtin_memcpy(&ua, &a, 2);
    __builtin_memcpy(&ub, &b, 2);
    return (unsigned)ua | ((unsigned)ub << 16);
}

typedef const __attribute__((address_space(1))) unsigned int* as1_u32p;
typedef __attribute__((address_space(3))) unsigned int* as3_u32p;
__device__ __forceinline__ void async_ld16(const void* g, const void* l) {
    __builtin_amdgcn_global_load_lds((as1_u32p)(unsigned long long)g,
                                     (as3_u32p)(unsigned int)(unsigned long long)l,
                                     16, 0, 0);
}

#define MFMA16(a,b,c) __builtin_amdgcn_mfma_f32_16x16x32_bf16((a),(b),(c),0,0,0)

// weights-only conversion: 4 mats x 288 blocks (af conversion fused into gemm_qkv)
__global__ __launch_bounds__(256)
void cvt_w(const float* __restrict__ Wq, const float* __restrict__ Wk,
           const float* __restrict__ Wv, const float* __restrict__ Wo,
           bf16* __restrict__ Wcat, bf16* __restrict__ Wobf)
{
    const int r = blockIdx.x;
    const int mat = r / 288, local = r % 288;
    const float* src = mat==0 ? Wq : mat==1 ? Wk : mat==2 ? Wv : Wo;
    bf16* dst = (mat < 3) ? (Wcat + (size_t)mat*589824) : Wobf;
    const size_t off = ((size_t)local*256 + threadIdx.x)*8;
    float4 a = *(const float4*)(src + off);
    float4 c = *(const float4*)(src + off + 4);
    uint4 o = { pk2(a.x,a.y), pk2(a.z,a.w), pk2(c.x,c.y), pk2(c.z,c.w) };
    *(uint4*)(dst + off) = o;
}

// ---------------------------------------------------------------------------
// 256x256 tile, BK=64, 8-wave, 2-zone mid-barrier core (best measured: 149us,
// 0 bank conflicts).  Template AF32:
//  false (gemm_o): A+B staged via global_load_lds; B(T+1) zone1 (other buf),
//        A(T+2) zone2 (current buf); end vmcnt(4), tail vmcnt(0)@T==10.
//  true (gemm_qkv): A is f32 in HBM; zone1 issues 8x global_load_dwordx4 of
//        A(T+1) to regs (hidden under Q0/Q1 MFMA; compiler's counted vmcnt at
//        the ds_write data-dep leaves B's gld_lds in flight); zone2 converts
//        (pk2) and ds_write_b128 into the OTHER buffer (its readers drained
//        lgkmcnt(0) before barrier(T-1)).  ds_write layout == gld_lds layout:
//        LDS slot s of row r holds k-chunk s^(r&7) -> same 0-conflict banks.
//        End-of-tile: lgkmcnt(0) (reads+writes) + vmcnt(0) (B only, issued a
//        full tile earlier -> free).
// ---------------------------------------------------------------------------
template<bool AF32>
__device__ __forceinline__ void gemm256_core(
    const void* __restrict__ Avp, const bf16* __restrict__ Wp,
    int rowBase, int colBase, char* sm, f32x4 (&acc)[8][4])
{
    const bf16*  Ab = (const bf16*)Avp;
    const float* Af = (const float*)Avp;
    const int t = threadIdx.x;
    const int w = t >> 6, lane = t & 63, quad = lane >> 4, r16 = lane & 15;
    const int wr = w >> 2, wc = w & 3;
    // gld_lds staging decomposition (B always; A when !AF32)
    const int r0  = t >> 3;
    const int kbe = (((t & 7) ^ (r0 & 7)) << 3);   // pre-swizzled source col (elems)
    // f32 reg-staging (AF32): linear global col, swizzled LDS dest slot
    const int fcol   = (t & 7) * 8;
    const int wslot0 = ((t & 7) ^ (r0 & 7)) << 4;  // (r0+64k)&7 == r0&7
    // ds_read bases (byte offsets inside a buffer)
    const int aBase = (wr*128 + r16) * 128;
    const int bBase = 32768 + (wc*64 + r16) * 128;
    const int swz = (r16 & 7) << 4;
    const int cs0 = (0  + quad*16) ^ swz;
    const int cs1 = (64 + quad*16) ^ swz;

#pragma unroll
    for (int i = 0; i < 8; ++i)
#pragma unroll
        for (int j = 0; j < 4; ++j) acc[i][j] = (f32x4){0.f,0.f,0.f,0.f};

    auto stageG = [&](int isB, int T, int h) {
        const bf16* g = isB ? Wp : Ab;
        const int gr0 = (isB ? colBase : rowBase) + h*128 + r0;
        const bf16* p0 = g + (size_t)gr0*768 + T*64 + kbe;
        char* dst = sm + ((T&1)*65536 + isB*32768 + h*16384 + w*1024);
        async_ld16(p0, dst);
        async_ld16(p0 + (size_t)64*768, dst + 8192);
    };

    // AF32 staging registers (named, static indexing)
    float4 a00,a01,a10,a11,a20,a21,a30,a31;
    auto loadA = [&](int T){
        const float* pa = Af + (size_t)(rowBase + r0)*768 + T*64 + fcol;
        a00 = *(const float4*)(pa);             a01 = *(const float4*)(pa + 4);
        a10 = *(const float4*)(pa +  64*768);   a11 = *(const float4*)(pa +  64*768 + 4);
        a20 = *(const float4*)(pa + 128*768);   a21 = *(const float4*)(pa + 128*768 + 4);
        a30 = *(const float4*)(pa + 192*768);   a31 = *(const float4*)(pa + 192*768 + 4);
    };
    auto writeA = [&](int T){
        char* ab = sm + (T&1)*65536;
        uint4 o0 = { pk2(a00.x,a00.y), pk2(a00.z,a00.w), pk2(a01.x,a01.y), pk2(a01.z,a01.w) };
        uint4 o1 = { pk2(a10.x,a10.y), pk2(a10.z,a10.w), pk2(a11.x,a11.y), pk2(a11.z,a11.w) };
        uint4 o2 = { pk2(a20.x,a20.y), pk2(a20.z,a20.w), pk2(a21.x,a21.y), pk2(a21.z,a21.w) };
        uint4 o3 = { pk2(a30.x,a30.y), pk2(a30.z,a30.w), pk2(a31.x,a31.y), pk2(a31.z,a31.w) };
        *(uint4*)(ab + (r0      )*128 + wslot0) = o0;
        *(uint4*)(ab + (r0 +  64)*128 + wslot0) = o1;
        *(uint4*)(ab + (r0 + 128)*128 + wslot0) = o2;
        *(uint4*)(ab + (r0 + 192)*128 + wslot0) = o3;
    };

    // prologue
    if constexpr (AF32) {
        loadA(0);
        stageG(1,0,0); stageG(1,0,1);
        writeA(0);                         // data-dep waits the A loads
        asm volatile("s_waitcnt vmcnt(0) lgkmcnt(0)" ::: "memory");
        __builtin_amdgcn_s_barrier();
    } else {
        stageG(0,0,0); stageG(0,0,1); stageG(1,0,0); stageG(1,0,1);
        stageG(0,1,0); stageG(0,1,1);
        asm volatile("s_waitcnt vmcnt(4)" ::: "memory");
        __builtin_amdgcn_s_barrier();
    }

    bf16x8 fa0[4][2], fa1[4][2], b0v[2][2], b1v[2][2];

    for (int T = 0; T < 12; ++T) {
        const char* Bf = sm + (T&1)*65536;

        // ---------------- zone 1 ----------------
        if (AF32 && T+1 < 12) loadA(T+1);
        if (T+1 < 12) { stageG(1, T+1, 0); stageG(1, T+1, 1); }
#pragma unroll
        for (int mi = 0; mi < 4; ++mi) {
            fa0[mi][0] = *(const bf16x8*)(Bf + aBase + mi*2048 + cs0);
            fa0[mi][1] = *(const bf16x8*)(Bf + aBase + mi*2048 + cs1);
        }
#pragma unroll
        for (int ni = 0; ni < 2; ++ni) {
            b0v[ni][0] = *(const bf16x8*)(Bf + bBase + ni*2048 + cs0);
            b0v[ni][1] = *(const bf16x8*)(Bf + bBase + ni*2048 + cs1);
        }
        __builtin_amdgcn_s_setprio(1);
#pragma unroll
        for (int mi = 0; mi < 4; ++mi)
#pragma unroll
            for (int ni = 0; ni < 2; ++ni) {
                acc[mi][ni] = MFMA16(fa0[mi][0], b0v[ni][0], acc[mi][ni]);
                acc[mi][ni] = MFMA16(fa0[mi][1], b0v[ni][1], acc[mi][ni]);
            }
        __builtin_amdgcn_s_setprio(0);
#pragma unroll
        for (int mi = 0; mi < 4; ++mi) {
            fa1[mi][0] = *(const bf16x8*)(Bf + aBase + 8192 + mi*2048 + cs0);
            fa1[mi][1] = *(const bf16x8*)(Bf + aBase + 8192 + mi*2048 + cs1);
        }
        __builtin_amdgcn_s_setprio(1);
#pragma unroll
        for (int mi = 0; mi < 4; ++mi)
#pragma unroll
            for (int ni = 0; ni < 2; ++ni) {
                acc[4+mi][ni] = MFMA16(fa1[mi][0], b0v[ni][0], acc[4+mi][ni]);
                acc[4+mi][ni] = MFMA16(fa1[mi][1], b0v[ni][1], acc[4+mi][ni]);
            }
        __builtin_amdgcn_s_setprio(0);
#pragma unroll
        for (int ni = 0; ni < 2; ++ni) {
            b1v[ni][0] = *(const bf16x8*)(Bf + bBase + 4096 + ni*2048 + cs0);
            b1v[ni][1] = *(const bf16x8*)(Bf + bBase + 4096 + ni*2048 + cs1);
        }
        asm volatile("s_waitcnt lgkmcnt(0)" ::: "memory");
        __builtin_amdgcn_sched_barrier(0);
        __builtin_amdgcn_s_barrier();          // mid barrier

        // ---------------- zone 2 ----------------
        if constexpr (AF32) {
            if (T+1 < 12) writeA(T+1);         // other buffer, readers long gone
        } else {
            if (T+2 < 12) { stageG(0, T+2, 0); stageG(0, T+2, 1); }
        }
        __builtin_amdgcn_s_setprio(1);
#pragma unroll
        for (int mi = 0; mi < 4; ++mi)
#pragma unroll
            for (int ni = 0; ni < 2; ++ni) {
                acc[mi][2+ni] = MFMA16(fa0[mi][0], b1v[ni][0], acc[mi][2+ni]);
                acc[mi][2+ni] = MFMA16(fa0[mi][1], b1v[ni][1], acc[mi][2+ni]);
            }
#pragma unroll
        for (int mi = 0; mi < 4; ++mi)
#pragma unroll
            for (int ni = 0; ni < 2; ++ni) {
                acc[4+mi][2+ni] = MFMA16(fa1[mi][0], b1v[ni][0], acc[4+mi][2+ni]);
                acc[4+mi][2+ni] = MFMA16(fa1[mi][1], b1v[ni][1], acc[4+mi][2+ni]);
            }
        __builtin_amdgcn_s_setprio(0);
        if constexpr (AF32) {
            asm volatile("s_waitcnt lgkmcnt(0)" ::: "memory");   // ds_writes drained
            if (T+1 < 12) { asm volatile("s_waitcnt vmcnt(0)" ::: "memory"); }
        } else {
            if (T < 10)       { asm volatile("s_waitcnt vmcnt(4)" ::: "memory"); }
            else if (T == 10) { asm volatile("s_waitcnt vmcnt(0)" ::: "memory"); }
        }
        if (T < 11) __builtin_amdgcn_s_barrier();
    }
}

// fused QKV GEMM (A = f32 atom_features): grid 1152 = 8 XCD x (16 row x 9 col)
__global__ __launch_bounds__(512, 2)
void gemm_qkv(const float* __restrict__ A, const bf16* __restrict__ W,
              const float* __restrict__ bq, const float* __restrict__ bk,
              const float* __restrict__ bv,
              bf16* __restrict__ qb, bf16* __restrict__ kb, bf16* __restrict__ vb)
{
    __shared__ __align__(16) char sm[131072];
    const int bid = blockIdx.x;
    const int xcd = bid & 7, idx = bid >> 3;           // idx 0..143
    const int rowBlk = xcd*16 + idx/9;
    const int colBlk = idx - (idx/9)*9;
    const int rowBase = rowBlk * 256;
    const int colBase = colBlk * 256;

    f32x4 acc[8][4];
    gemm256_core<true>(A, W, rowBase, colBase, sm, acc);

    const int t = threadIdx.x;
    const int w = t >> 6, lane = t & 63, quad = lane >> 4, r16 = lane & 15;
    const int wr = w >> 2, wc = w & 3;
    const int sel = colBlk / 3;                        // 0=q 1=k 2=v
    const float* bias = sel==0 ? bq : sel==1 ? bk : bv;
    bf16* C = sel==0 ? qb : sel==1 ? kb : vb;
    const int colSec = colBase - sel*768;
#pragma unroll
    for (int nj = 0; nj < 4; ++nj) {
        int col = colSec + wc*64 + nj*16 + r16;
        float bb = bias[col];
#pragma unroll
        for (int mi = 0; mi < 8; ++mi) {
            int row0 = rowBase + wr*128 + mi*16 + quad*4;
#pragma unroll
            for (int rr = 0; rr < 4; ++rr)
                C[(size_t)(row0+rr)*768 + col] = f2bf(acc[mi][nj][rr] + bb);
        }
    }
}

// Wo projection (A = bf16 ctx): grid 384 = 8 XCD x (16 row x 3 col)
__global__ __launch_bounds__(512, 2)
void gemm_o(const bf16* __restrict__ A, const bf16* __restrict__ W,
            const float* __restrict__ bo, bf16* __restrict__ C)
{
    __shared__ __align__(16) char sm[131072];
    const int bid = blockIdx.x;
    const int xcd = bid & 7, idx = bid >> 3;           // idx 0..47
    const int rowBlk = xcd*16 + idx/3;
    const int colBlk = idx - (idx/3)*3;
    const int rowBase = rowBlk * 256;
    const int colBase = colBlk * 256;

    f32x4 acc[8][4];
    gemm256_core<false>(A, W, rowBase, colBase, sm, acc);

    const int t = threadIdx.x;
    const int w = t >> 6, lane = t & 63, quad = lane >> 4, r16 = lane & 15;
    const int wr = w >> 2, wc = w & 3;
#pragma unroll
    for (int nj = 0; nj < 4; ++nj) {
        int col = colBase + wc*64 + nj*16 + r16;
        float bb = bo[col];
#pragma unroll
        for (int mi = 0; mi < 8; ++mi) {
            int row0 = rowBase + wr*128 + mi*16 + quad*4;
#pragma unroll
            for (int rr = 0; rr < 4; ++rr)
                C[(size_t)(row0+rr)*768 + col] = f2bf(acc[mi][nj][rr] + bb);
        }
    }
}

// one block per (m, nh); 256 threads = 4 waves; 4 passes of 64 q rows.
// K fragments hoisted into registers (loaded once, reused all 4 passes).
__global__ __launch_bounds__(256, 2)
void attn_kernel(const bf16* __restrict__ qbuf, const bf16* __restrict__ kbuf,
                 bf16* vctx, const int* __restrict__ a_sizes)
{
    __shared__ __align__(16) bf16 VT[64*264];
    __shared__ __align__(16) bf16 P[4*16*264];

    const int b = blockIdx.x;
    const int m = b / NH_, nh = b % NH_;
    const int t = threadIdx.x;
    const int w = t >> 6, lane = t & 63, quad = lane >> 4, r16 = lane & 15;
    const int size = a_sizes[m];
    const size_t headOff = (size_t)m*L_SEQ*768 + nh*64;

    {
        const int k0 = (t & 127) * 2;
        const int dh = (t >> 7) * 32;
        const bf16* v0 = vctx + headOff + (size_t)k0*768 + dh;
        const bf16* v1 = v0 + 768;
        u16x8 r0[4], r1[4];
#pragma unroll
        for (int c = 0; c < 4; ++c) {
            r0[c] = *(const u16x8*)(v0 + c*8);
            r1[c] = *(const u16x8*)(v1 + c*8);
        }
#pragma unroll
        for (int c = 0; c < 4; ++c)
#pragma unroll
            for (int j = 0; j < 8; ++j) {
                unsigned val = (unsigned)r0[c][j] | ((unsigned)r1[c][j] << 16);
                *(unsigned*)(&VT[(size_t)(dh + c*8 + j)*264 + k0]) = val;
            }
    }
    __syncthreads();

    // hoist K fragments: full head K-slice per wave, once
    bf16x8 kf0[16], kf1[16];
#pragma unroll
    for (int kt = 0; kt < 16; ++kt) {
        const bf16* krow = kbuf + headOff + (size_t)(kt*16 + r16)*768 + quad*8;
        kf0[kt] = *(const bf16x8*)(krow);
        kf1[kt] = *(const bf16x8*)(krow + 32);
    }

    bf16* Pw = P + w*16*264;
    for (int pass = 0; pass < 4; ++pass) {
        const int qrow0 = pass*64 + w*16;
        bf16x8 aq0, aq1;
        {
            const bf16* qrow = qbuf + headOff + (size_t)(qrow0 + r16)*768 + quad*8;
            aq0 = *(const bf16x8*)(qrow);
            aq1 = *(const bf16x8*)(qrow + 32);
        }
        f32x4 S[16];
#pragma unroll
        for (int kt = 0; kt < 16; ++kt) {
            f32x4 s = (f32x4){0.f,0.f,0.f,0.f};
            s = __builtin_amdgcn_mfma_f32_16x16x32_bf16(aq0, kf0[kt], s, 0, 0, 0);
            s = __builtin_amdgcn_mfma_f32_16x16x32_bf16(aq1, kf1[kt], s, 0, 0, 0);
            S[kt] = s;
        }
        float mrow[4] = {-1e30f,-1e30f,-1e30f,-1e30f};
#pragma unroll
        for (int kt = 0; kt < 16; ++kt) {
            int key = kt*16 + r16;
#pragma unroll
            for (int rr = 0; rr < 4; ++rr) {
                float s = S[kt][rr] * 0.125f;
                if (key >= size) s = -1e9f;
                S[kt][rr] = s;
                mrow[rr] = fmaxf(mrow[rr], s);
            }
        }
#pragma unroll
        for (int msk = 1; msk < 16; msk <<= 1)
#pragma unroll
            for (int rr = 0; rr < 4; ++rr)
                mrow[rr] = fmaxf(mrow[rr], __shfl_xor(mrow[rr], msk));
        float lrow[4] = {0.f,0.f,0.f,0.f};
#pragma unroll
        for (int kt = 0; kt < 16; ++kt) {
#pragma unroll
            for (int rr = 0; rr < 4; ++rr) {
                float p = __expf(S[kt][rr] - mrow[rr]);
                lrow[rr] += p;
                Pw[(quad*4+rr)*264 + kt*16 + r16] = f2bf(p);
            }
        }
#pragma unroll
        for (int msk = 1; msk < 16; msk <<= 1)
#pragma unroll
            for (int rr = 0; rr < 4; ++rr)
                lrow[rr] += __shfl_xor(lrow[rr], msk);
        asm volatile("s_waitcnt lgkmcnt(0)" ::: "memory");

        bf16x8 pa[8];
#pragma unroll
        for (int kb2 = 0; kb2 < 8; ++kb2)
            pa[kb2] = *(const bf16x8*)(&Pw[r16*264 + kb2*32 + quad*8]);
        float inv[4];
#pragma unroll
        for (int rr = 0; rr < 4; ++rr) inv[rr] = 1.f / lrow[rr];
#pragma unroll
        for (int dt = 0; dt < 4; ++dt) {
            f32x4 c = (f32x4){0.f,0.f,0.f,0.f};
#pragma unroll
            for (int kb2 = 0; kb2 < 8; ++kb2) {
                bf16x8 vb8 = *(const bf16x8*)(&VT[(dt*16 + r16)*264 + kb2*32 + quad*8]);
                c = __builtin_amdgcn_mfma_f32_16x16x32_bf16(pa[kb2], vb8, c, 0, 0, 0);
            }
#pragma unroll
            for (int rr = 0; rr < 4; ++rr) {
                int q = qrow0 + quad*4 + rr;
                vctx[headOff + (size_t)q*768 + dt*16 + r16] = f2bf(c[rr] * inv[rr]);
            }
        }
    }
}

__global__ __launch_bounds__(256, 4)
void ln_kernel(const bf16* __restrict__ proj, const float* __restrict__ af,
               const float* __restrict__ gamma, const float* __restrict__ beta,
               const int* __restrict__ a_sizes, float* __restrict__ out)
{
    const int w = threadIdx.x >> 6, lane = threadIdx.x & 63;
    const int n = blockIdx.x * 4 + w;
    const int m = n >> 8, l = n & 255;
    const int size = a_sizes[m];
    float* orow = out + (size_t)n * 768;
    if (l >= size) {
        float4 z = {0.f,0.f,0.f,0.f};
#pragma unroll
        for (int i = 0; i < 3; ++i) *(float4*)(&orow[i*256 + lane*4]) = z;
        return;
    }
    const bf16*  prow = proj + (size_t)n * 768;
    const float* xrow = af   + (size_t)n * 768;
    float y[3][4];
    float s = 0.f;
#pragma unroll
    for (int i = 0; i < 3; ++i) {
        int c = i*256 + lane*4;
        float4 xv = *(const float4*)(&xrow[c]);
        ushort4 pv = *(const ushort4*)(&prow[c]);
        y[i][0] = xv.x + bfbits2f(pv.x);
        y[i][1] = xv.y + bfbits2f(pv.y);
        y[i][2] = xv.z + bfbits2f(pv.z);
        y[i][3] = xv.w + bfbits2f(pv.w);
        s += y[i][0] + y[i][1] + y[i][2] + y[i][3];
    }
#pragma unroll
    for (int msk = 1; msk < 64; msk <<= 1) s += __shfl_xor(s, msk);
    float mu = s * (1.f/768.f);
    float v = 0.f;
#pragma unroll
    for (int i = 0; i < 3; ++i)
#pragma unroll
        for (int j = 0; j < 4; ++j) { float d = y[i][j] - mu; v += d*d; }
#pragma unroll
    for (int msk = 1; msk < 64; msk <<= 1) v += __shfl_xor(v, msk);
    float rstd = rsqrtf(v * (1.f/768.f) + 1e-5f);
#pragma unroll
    for (int i = 0; i < 3; ++i) {
        int c = i*256 + lane*4;
        float4 gv = *(const float4*)(&gamma[c]);
        float4 bv = *(const float4*)(&beta[c]);
        float4 o;
        o.x = (y[i][0] - mu) * rstd * gv.x + bv.x;
        o.y = (y[i][1] - mu) * rstd * gv.y + bv.y;
        o.z = (y[i][2] - mu) * rstd * gv.z + bv.z;
        o.w = (y[i][3] - mu) * rstd * gv.w + bv.w;
        *(float4*)(&orow[c]) = o;
    }
}

extern "C" void kernel_launch(void* const* d_in, const int* in_sizes, int n_in,
                              void* d_out, int out_size, void* d_ws, size_t ws_size,
                              hipStream_t stream)
{
    (void)in_sizes; (void)n_in; (void)out_size; (void)ws_size;
    const float* af    = (const float*)d_in[0];
    const float* Wq    = (const float*)d_in[1];
    const float* bq    = (const float*)d_in[2];
    const float* Wk    = (const float*)d_in[3];
    const float* bk    = (const float*)d_in[4];
    const float* Wv    = (const float*)d_in[5];
    const float* bv    = (const float*)d_in[6];
    const float* Wo    = (const float*)d_in[7];
    const float* bo    = (const float*)d_in[8];
    const float* gamma = (const float*)d_in[9];
    const float* beta  = (const float*)d_in[10];
    const int* a_sizes = (const int*)d_in[12];
    float* outp = (float*)d_out;

    // d_ws: qb, kb, vb (bf16 N x 768 each = 144 MiB; proven ws >= 192 MiB)
    bf16* qb = (bf16*)d_ws;
    bf16* kb = qb + (size_t)N_TOT * 768;
    bf16* vb = kb + (size_t)N_TOT * 768;          // ctx overwrites in place
    // d_out doubles as scratch until ln_kernel overwrites it (stream-ordered):
    // Wcat 3.4 MB + Wobf 1.1 MB << 100.6 MB output buffer; both consumed
    // before ln_kernel writes out.
    bf16* Wcat = (bf16*)d_out;
    bf16* Wobf = Wcat + (size_t)2304 * 768;

    cvt_w<<<dim3(4*288), 256, 0, stream>>>(Wq, Wk, Wv, Wo, Wcat, Wobf);
    gemm_qkv<<<dim3(1152), 512, 0, stream>>>(af, Wcat, bq, bk, bv, qb, kb, vb);
    attn_kernel<<<dim3(M_MOL * NH_), 256, 0, stream>>>(qb, kb, vb, a_sizes);
    gemm_o<<<dim3(384), 512, 0, stream>>>(vb, Wobf, bo, qb);
    ln_kernel<<<dim3(N_TOT / 4), 256, 0, stream>>>(qb, af, gamma, beta, a_sizes, outp);
}

// Round 8
// 468.686 us; speedup vs baseline: 1.1728x; 1.1728x over previous
//
#include <hip/hip_runtime.h>
#include <hip/hip_bf16.h>
#include <stdint.h>

#define M_MOL 128
#define L_SEQ 256
#define H_DIM 768
#define NH_   12
#define HD_   64
#define N_TOT (M_MOL * L_SEQ)

typedef __attribute__((ext_vector_type(8))) short bf16x8;
typedef __attribute__((ext_vector_type(4))) float f32x4;
typedef __attribute__((ext_vector_type(8))) unsigned short u16x8;
typedef __hip_bfloat16 bf16;

__device__ __forceinline__ float bf2f(bf16 x){ return __bfloat162float(x); }
__device__ __forceinline__ bf16 f2bf(float x){ return __float2bfloat16(x); }
__device__ __forceinline__ float bfbits2f(unsigned short u){
    return __uint_as_float(((unsigned)u) << 16);
}
__device__ __forceinline__ unsigned pk2(float lo, float hi){
    bf16 a = f2bf(lo), b = f2bf(hi);
    unsigned short ua, ub;
    __builtin_memcpy(&ua, &a, 2);
    __builtin_memcpy(&ub, &b, 2);
    return (unsigned)ua | ((unsigned)ub << 16);
}

typedef const __attribute__((address_space(1))) unsigned int* as1_u32p;
typedef __attribute__((address_space(3))) unsigned int* as3_u32p;
__device__ __forceinline__ void async_ld16(const void* g, const void* l) {
    __builtin_amdgcn_global_load_lds((as1_u32p)(unsigned long long)g,
                                     (as3_u32p)(unsigned int)(unsigned long long)l,
                                     16, 0, 0);
}

#define MFMA16(a,b,c) __builtin_amdgcn_mfma_f32_16x16x32_bf16((a),(b),(c),0,0,0)

// one kernel converts atom_features (12288 blocks) + 4 weight mats (288 each)
__global__ __launch_bounds__(256)
void cvt_all(const float* __restrict__ af, const float* __restrict__ Wq,
             const float* __restrict__ Wk, const float* __restrict__ Wv,
             const float* __restrict__ Wo,
             bf16* __restrict__ afb, bf16* __restrict__ Wcat, bf16* __restrict__ Wobf)
{
    const int b = blockIdx.x;
    const float* src; bf16* dst; int local;
    if (b < 12288) { src = af; dst = afb; local = b; }
    else {
        int r = b - 12288;
        int mat = r / 288; local = r % 288;
        src = mat==0 ? Wq : mat==1 ? Wk : mat==2 ? Wv : Wo;
        dst = (mat < 3) ? (Wcat + (size_t)mat*589824) : Wobf;
    }
    const size_t off = ((size_t)local*256 + threadIdx.x)*8;
    float4 a = *(const float4*)(src + off);
    float4 c = *(const float4*)(src + off + 4);
    uint4 o = { pk2(a.x,a.y), pk2(a.z,a.w), pk2(c.x,c.y), pk2(c.z,c.w) };
    *(uint4*)(dst + off) = o;
}

// ---------------------------------------------------------------------------
// 128x128 tile, BK=64, 4-wave (2x2), 2-zone mid-barrier core.
// Same proven schedule/swizzle as the 149us 256^2 core, but 64 KiB LDS ->
// TWO blocks/CU: independent block fills the other block's barrier/vmcnt
// bubbles (the 256^2 core's measured limiter at 1 block/CU).
//   zone1: stage B(T+1) (other buf); read all A frags + B nj0-1; MFMA half 1;
//          read B nj2-3; lgkmcnt(0); mid-barrier.
//   zone2: stage A(T+2) (current buf, safe after mid-barrier); MFMA half 2;
//          vmcnt(4) retires exactly A(T+1)+B(T+1), leaves A(T+2) in flight.
// LDS: 2 buf x (A 128x64 + B 128x64) bf16 = 64 KiB; involution swizzle
// (16B slot ^= row&7 within 128B rows), staged via inverse-swizzled source.
// ---------------------------------------------------------------------------
__device__ __forceinline__ void gemm128_core(
    const bf16* __restrict__ Ap, const bf16* __restrict__ Wp,
    int rowBase, int colBase, char* sm, f32x4 (&acc)[4][4])
{
    const int t = threadIdx.x;
    const int w = t >> 6, lane = t & 63, quad = lane >> 4, r16 = lane & 15;
    const int wr = w >> 1, wc = w & 1;
    // staging: thread t covers rows r0+32p, slot t&7 holds k-chunk (t&7)^(r0&7)
    const int r0  = t >> 3;                        // 0..31
    const int kbe = (((t & 7) ^ (r0 & 7)) << 3);   // pre-swizzled source col (elems)
    // ds_read bases (byte offsets inside a buffer)
    const int aBase = (wr*64 + r16) * 128;
    const int bBase = 16384 + (wc*64 + r16) * 128;
    const int swz = (r16 & 7) << 4;
    const int cs0 = (0  + quad*16) ^ swz;          // k-step 0
    const int cs1 = (64 + quad*16) ^ swz;          // k-step 1

#pragma unroll
    for (int i = 0; i < 4; ++i)
#pragma unroll
        for (int j = 0; j < 4; ++j) acc[i][j] = (f32x4){0.f,0.f,0.f,0.f};

    // stage one full 128x64 matrix (16 KiB, 4 async calls) for K-tile T
    auto stage = [&](int isB, int T) {
        const bf16* g = isB ? Wp : Ap;
        const int gr0 = (isB ? colBase : rowBase) + r0;
        const bf16* p0 = g + (size_t)gr0*768 + T*64 + kbe;
        char* dst = sm + ((T&1)*32768 + isB*16384 + w*1024);
#pragma unroll
        for (int p = 0; p < 4; ++p)
            async_ld16(p0 + (size_t)p*32*768, dst + p*4096);
    };

    // prologue: A(0), B(0), A(1); vmcnt(4) retires tile 0, leaves A(1)
    stage(0,0); stage(1,0); stage(0,1);
    asm volatile("s_waitcnt vmcnt(4)" ::: "memory");
    __builtin_amdgcn_s_barrier();

    bf16x8 av[4][2], bv[4][2];

    for (int T = 0; T < 12; ++T) {
        const char* Bf = sm + (T&1)*32768;

        // ---------------- zone 1 ----------------
        if (T+1 < 12) stage(1, T+1);
#pragma unroll
        for (int mi = 0; mi < 4; ++mi) {
            av[mi][0] = *(const bf16x8*)(Bf + aBase + mi*2048 + cs0);
            av[mi][1] = *(const bf16x8*)(Bf + aBase + mi*2048 + cs1);
        }
#pragma unroll
        for (int nj = 0; nj < 2; ++nj) {
            bv[nj][0] = *(const bf16x8*)(Bf + bBase + nj*2048 + cs0);
            bv[nj][1] = *(const bf16x8*)(Bf + bBase + nj*2048 + cs1);
        }
        __builtin_amdgcn_s_setprio(1);
#pragma unroll
        for (int mi = 0; mi < 4; ++mi)
#pragma unroll
            for (int nj = 0; nj < 2; ++nj) {
                acc[mi][nj] = MFMA16(av[mi][0], bv[nj][0], acc[mi][nj]);
                acc[mi][nj] = MFMA16(av[mi][1], bv[nj][1], acc[mi][nj]);
            }
        __builtin_amdgcn_s_setprio(0);
#pragma unroll
        for (int nj = 2; nj < 4; ++nj) {
            bv[nj][0] = *(const bf16x8*)(Bf + bBase + nj*2048 + cs0);
            bv[nj][1] = *(const bf16x8*)(Bf + bBase + nj*2048 + cs1);
        }
        asm volatile("s_waitcnt lgkmcnt(0)" ::: "memory");
        __builtin_amdgcn_sched_barrier(0);
        __builtin_amdgcn_s_barrier();          // mid barrier

        // ---------------- zone 2 ----------------
        if (T+2 < 12) stage(0, T+2);           // current buf A, readers drained
        __builtin_amdgcn_s_setprio(1);
#pragma unroll
        for (int mi = 0; mi < 4; ++mi)
#pragma unroll
            for (int nj = 2; nj < 4; ++nj) {
                acc[mi][nj] = MFMA16(av[mi][0], bv[nj][0], acc[mi][nj]);
                acc[mi][nj] = MFMA16(av[mi][1], bv[nj][1], acc[mi][nj]);
            }
        __builtin_amdgcn_s_setprio(0);
        if (T < 10)       { asm volatile("s_waitcnt vmcnt(4)" ::: "memory"); }
        else if (T == 10) { asm volatile("s_waitcnt vmcnt(0)" ::: "memory"); }
        if (T < 11) __builtin_amdgcn_s_barrier();
    }
}

// fused QKV GEMM: grid 4608 = 8 XCD x (32 rowBlk x 18 colBlk), col fastest
__global__ __launch_bounds__(256, 2)
void gemm_qkv(const bf16* __restrict__ A, const bf16* __restrict__ W,
              const float* __restrict__ bq, const float* __restrict__ bk,
              const float* __restrict__ bv,
              bf16* __restrict__ qb, bf16* __restrict__ kb, bf16* __restrict__ vb)
{
    __shared__ __align__(16) char sm[65536];
    const int bid = blockIdx.x;
    const int xcd = bid & 7, idx = bid >> 3;           // idx 0..575
    const int rowBlk = xcd*32 + idx/18;
    const int colBlk = idx - (idx/18)*18;
    const int rowBase = rowBlk * 128;
    const int colBase = colBlk * 128;

    f32x4 acc[4][4];
    gemm128_core(A, W, rowBase, colBase, sm, acc);

    const int t = threadIdx.x;
    const int w = t >> 6, lane = t & 63, quad = lane >> 4, r16 = lane & 15;
    const int wr = w >> 1, wc = w & 1;
    const int sel = colBlk / 6;                        // 0=q 1=k 2=v
    const float* bias = sel==0 ? bq : sel==1 ? bk : bv;
    bf16* C = sel==0 ? qb : sel==1 ? kb : vb;
    const int colSec = colBase - sel*768;
#pragma unroll
    for (int nj = 0; nj < 4; ++nj) {
        int col = colSec + wc*64 + nj*16 + r16;
        float bb = bias[col];
#pragma unroll
        for (int mi = 0; mi < 4; ++mi) {
            int row0 = rowBase + wr*64 + mi*16 + quad*4;
#pragma unroll
            for (int rr = 0; rr < 4; ++rr)
                C[(size_t)(row0+rr)*768 + col] = f2bf(acc[mi][nj][rr] + bb);
        }
    }
}

// Wo projection: grid 1536 = 8 XCD x (32 rowBlk x 6 colBlk), col fastest
__global__ __launch_bounds__(256, 2)
void gemm_o(const bf16* __restrict__ A, const bf16* __restrict__ W,
            const float* __restrict__ bo, bf16* __restrict__ C)
{
    __shared__ __align__(16) char sm[65536];
    const int bid = blockIdx.x;
    const int xcd = bid & 7, idx = bid >> 3;           // idx 0..191
    const int rowBlk = xcd*32 + idx/6;
    const int colBlk = idx - (idx/6)*6;
    const int rowBase = rowBlk * 128;
    const int colBase = colBlk * 128;

    f32x4 acc[4][4];
    gemm128_core(A, W, rowBase, colBase, sm, acc);

    const int t = threadIdx.x;
    const int w = t >> 6, lane = t & 63, quad = lane >> 4, r16 = lane & 15;
    const int wr = w >> 1, wc = w & 1;
#pragma unroll
    for (int nj = 0; nj < 4; ++nj) {
        int col = colBase + wc*64 + nj*16 + r16;
        float bb = bo[col];
#pragma unroll
        for (int mi = 0; mi < 4; ++mi) {
            int row0 = rowBase + wr*64 + mi*16 + quad*4;
#pragma unroll
            for (int rr = 0; rr < 4; ++rr)
                C[(size_t)(row0+rr)*768 + col] = f2bf(acc[mi][nj][rr] + bb);
        }
    }
}

// one block per (m, nh); 256 threads = 4 waves; 4 passes of 64 q rows.
// K fragments hoisted into registers (loaded once, reused all 4 passes).
__global__ __launch_bounds__(256, 2)
void attn_kernel(const bf16* __restrict__ qbuf, const bf16* __restrict__ kbuf,
                 bf16* vctx, const int* __restrict__ a_sizes)
{
    __shared__ __align__(16) bf16 VT[64*264];
    __shared__ __align__(16) bf16 P[4*16*264];

    const int b = blockIdx.x;
    const int m = b / NH_, nh = b % NH_;
    const int t = threadIdx.x;
    const int w = t >> 6, lane = t & 63, quad = lane >> 4, r16 = lane & 15;
    const int size = a_sizes[m];
    const size_t headOff = (size_t)m*L_SEQ*768 + nh*64;

    {
        const int k0 = (t & 127) * 2;
        const int dh = (t >> 7) * 32;
        const bf16* v0 = vctx + headOff + (size_t)k0*768 + dh;
        const bf16* v1 = v0 + 768;
        u16x8 r0[4], r1[4];
#pragma unroll
        for (int c = 0; c < 4; ++c) {
            r0[c] = *(const u16x8*)(v0 + c*8);
            r1[c] = *(const u16x8*)(v1 + c*8);
        }
#pragma unroll
        for (int c = 0; c < 4; ++c)
#pragma unroll
            for (int j = 0; j < 8; ++j) {
                unsigned val = (unsigned)r0[c][j] | ((unsigned)r1[c][j] << 16);
                *(unsigned*)(&VT[(size_t)(dh + c*8 + j)*264 + k0]) = val;
            }
    }
    __syncthreads();

    // hoist K fragments: full head K-slice per wave, once
    bf16x8 kf0[16], kf1[16];
#pragma unroll
    for (int kt = 0; kt < 16; ++kt) {
        const bf16* krow = kbuf + headOff + (size_t)(kt*16 + r16)*768 + quad*8;
        kf0[kt] = *(const bf16x8*)(krow);
        kf1[kt] = *(const bf16x8*)(krow + 32);
    }

    bf16* Pw = P + w*16*264;
    for (int pass = 0; pass < 4; ++pass) {
        const int qrow0 = pass*64 + w*16;
        bf16x8 aq0, aq1;
        {
            const bf16* qrow = qbuf + headOff + (size_t)(qrow0 + r16)*768 + quad*8;
            aq0 = *(const bf16x8*)(qrow);
            aq1 = *(const bf16x8*)(qrow + 32);
        }
        f32x4 S[16];
#pragma unroll
        for (int kt = 0; kt < 16; ++kt) {
            f32x4 s = (f32x4){0.f,0.f,0.f,0.f};
            s = __builtin_amdgcn_mfma_f32_16x16x32_bf16(aq0, kf0[kt], s, 0, 0, 0);
            s = __builtin_amdgcn_mfma_f32_16x16x32_bf16(aq1, kf1[kt], s, 0, 0, 0);
            S[kt] = s;
        }
        float mrow[4] = {-1e30f,-1e30f,-1e30f,-1e30f};
#pragma unroll
        for (int kt = 0; kt < 16; ++kt) {
            int key = kt*16 + r16;
#pragma unroll
            for (int rr = 0; rr < 4; ++rr) {
                float s = S[kt][rr] * 0.125f;
                if (key >= size) s = -1e9f;
                S[kt][rr] = s;
                mrow[rr] = fmaxf(mrow[rr], s);
            }
        }
#pragma unroll
        for (int msk = 1; msk < 16; msk <<= 1)
#pragma unroll
            for (int rr = 0; rr < 4; ++rr)
                mrow[rr] = fmaxf(mrow[rr], __shfl_xor(mrow[rr], msk));
        float lrow[4] = {0.f,0.f,0.f,0.f};
#pragma unroll
        for (int kt = 0; kt < 16; ++kt) {
#pragma unroll
            for (int rr = 0; rr < 4; ++rr) {
                float p = __expf(S[kt][rr] - mrow[rr]);
                lrow[rr] += p;
                Pw[(quad*4+rr)*264 + kt*16 + r16] = f2bf(p);
            }
        }
#pragma unroll
        for (int msk = 1; msk < 16; msk <<= 1)
#pragma unroll
            for (int rr = 0; rr < 4; ++rr)
                lrow[rr] += __shfl_xor(lrow[rr], msk);
        asm volatile("s_waitcnt lgkmcnt(0)" ::: "memory");

        bf16x8 pa[8];
#pragma unroll
        for (int kb2 = 0; kb2 < 8; ++kb2)
            pa[kb2] = *(const bf16x8*)(&Pw[r16*264 + kb2*32 + quad*8]);
        float inv[4];
#pragma unroll
        for (int rr = 0; rr < 4; ++rr) inv[rr] = 1.f / lrow[rr];
#pragma unroll
        for (int dt = 0; dt < 4; ++dt) {
            f32x4 c = (f32x4){0.f,0.f,0.f,0.f};
#pragma unroll
            for (int kb2 = 0; kb2 < 8; ++kb2) {
                bf16x8 vb8 = *(const bf16x8*)(&VT[(dt*16 + r16)*264 + kb2*32 + quad*8]);
                c = __builtin_amdgcn_mfma_f32_16x16x32_bf16(pa[kb2], vb8, c, 0, 0, 0);
            }
#pragma unroll
            for (int rr = 0; rr < 4; ++rr) {
                int q = qrow0 + quad*4 + rr;
                vctx[headOff + (size_t)q*768 + dt*16 + r16] = f2bf(c[rr] * inv[rr]);
            }
        }
    }
}

__global__ __launch_bounds__(256, 4)
void ln_kernel(const bf16* __restrict__ proj, const float* __restrict__ af,
               const float* __restrict__ gamma, const float* __restrict__ beta,
               const int* __restrict__ a_sizes, float* __restrict__ out)
{
    const int w = threadIdx.x >> 6, lane = threadIdx.x & 63;
    const int n = blockIdx.x * 4 + w;
    const int m = n >> 8, l = n & 255;
    const int size = a_sizes[m];
    float* orow = out + (size_t)n * 768;
    if (l >= size) {
        float4 z = {0.f,0.f,0.f,0.f};
#pragma unroll
        for (int i = 0; i < 3; ++i) *(float4*)(&orow[i*256 + lane*4]) = z;
        return;
    }
    const bf16*  prow = proj + (size_t)n * 768;
    const float* xrow = af   + (size_t)n * 768;
    float y[3][4];
    float s = 0.f;
#pragma unroll
    for (int i = 0; i < 3; ++i) {
        int c = i*256 + lane*4;
        float4 xv = *(const float4*)(&xrow[c]);
        ushort4 pv = *(const ushort4*)(&prow[c]);
        y[i][0] = xv.x + bfbits2f(pv.x);
        y[i][1] = xv.y + bfbits2f(pv.y);
        y[i][2] = xv.z + bfbits2f(pv.z);
        y[i][3] = xv.w + bfbits2f(pv.w);
        s += y[i][0] + y[i][1] + y[i][2] + y[i][3];
    }
#pragma unroll
    for (int msk = 1; msk < 64; msk <<= 1) s += __shfl_xor(s, msk);
    float mu = s * (1.f/768.f);
    float v = 0.f;
#pragma unroll
    for (int i = 0; i < 3; ++i)
#pragma unroll
        for (int j = 0; j < 4; ++j) { float d = y[i][j] - mu; v += d*d; }
#pragma unroll
    for (int msk = 1; msk < 64; msk <<= 1) v += __shfl_xor(v, msk);
    float rstd = rsqrtf(v * (1.f/768.f) + 1e-5f);
#pragma unroll
    for (int i = 0; i < 3; ++i) {
        int c = i*256 + lane*4;
        float4 gv = *(const float4*)(&gamma[c]);
        float4 bv = *(const float4*)(&beta[c]);
        float4 o;
        o.x = (y[i][0] - mu) * rstd * gv.x + bv.x;
        o.y = (y[i][1] - mu) * rstd * gv.y + bv.y;
        o.z = (y[i][2] - mu) * rstd * gv.z + bv.z;
        o.w = (y[i][3] - mu) * rstd * gv.w + bv.w;
        *(float4*)(&orow[c]) = o;
    }
}

extern "C" void kernel_launch(void* const* d_in, const int* in_sizes, int n_in,
                              void* d_out, int out_size, void* d_ws, size_t ws_size,
                              hipStream_t stream)
{
    (void)in_sizes; (void)n_in; (void)out_size; (void)ws_size;
    const float* af    = (const float*)d_in[0];
    const float* Wq    = (const float*)d_in[1];
    const float* bq    = (const float*)d_in[2];
    const float* Wk    = (const float*)d_in[3];
    const float* bk    = (const float*)d_in[4];
    const float* Wv    = (const float*)d_in[5];
    const float* bv    = (const float*)d_in[6];
    const float* Wo    = (const float*)d_in[7];
    const float* bo    = (const float*)d_in[8];
    const float* gamma = (const float*)d_in[9];
    const float* beta  = (const float*)d_in[10];
    const int* a_sizes = (const int*)d_in[12];
    float* outp = (float*)d_out;

    // d_ws: qb, kb, vb (bf16 N x 768 each = 144 MiB; proven ws >= 192 MiB)
    bf16* qb = (bf16*)d_ws;
    bf16* kb = qb + (size_t)N_TOT * 768;
    bf16* vb = kb + (size_t)N_TOT * 768;          // ctx overwrites in place
    // d_out doubles as scratch until ln_kernel overwrites it (stream-ordered):
    // afb 50.3 MB + Wcat 3.4 MB + Wobf 1.1 MB < 100.6 MB output buffer
    bf16* afb  = (bf16*)d_out;
    bf16* Wcat = afb + (size_t)N_TOT * 768;
    bf16* Wobf = Wcat + (size_t)2304 * 768;

    cvt_all<<<dim3(12288 + 4*288), 256, 0, stream>>>(af, Wq, Wk, Wv, Wo, afb, Wcat, Wobf);
    gemm_qkv<<<dim3(4608), 256, 0, stream>>>(afb, Wcat, bq, bk, bv, qb, kb, vb);
    attn_kernel<<<dim3(M_MOL * NH_), 256, 0, stream>>>(qb, kb, vb, a_sizes);
    gemm_o<<<dim3(1536), 256, 0, stream>>>(vb, Wobf, bo, qb);
    ln_kernel<<<dim3(N_TOT / 4), 256, 0, stream>>>(qb, af, gamma, beta, a_sizes, outp);
}